// Round 1
// baseline (705.614 us; speedup 1.0000x reference)
//
#include <hip/hip_runtime.h>
#include <cstdint>
#include <cstddef>

#define NN 50000
#define NE 800000
#define INC 128
#define HIDC 256
#define NH 4
#define OUTC 40

__device__ __forceinline__ float lrelu(float x){ return x > 0.f ? x : 0.2f*x; }

// ---- edge dtype detection: int64 view of int32 pairs gives values >= 2^32 ----
__global__ __launch_bounds__(64) void k_detect(const long long* __restrict__ ei, int* __restrict__ flag){
  int t = threadIdx.x;
  long long v = ei[(long long)t * (NE/64)];
  bool ok = (v >= 0) && (v < NN);
  unsigned long long m = __ballot(ok);
  if (t == 0) *flag = (m == 0xFFFFFFFFFFFFFFFFull) ? 1 : 0;
}

__global__ __launch_bounds__(256) void k_convert(const void* __restrict__ ei, const int* __restrict__ flag,
                                                 int* __restrict__ src32, int* __restrict__ dst32){
  int e = blockIdx.x*256 + threadIdx.x;
  if (e >= NE) return;
  int s, d;
  if (*flag){
    const long long* p = (const long long*)ei;
    s = (int)p[e]; d = (int)p[NE+e];
  } else {
    const int* p = (const int*)ei;
    s = p[e]; d = p[NE+e];
  }
  s = min(max(s,0),NN-1); d = min(max(d,0),NN-1);
  src32[e] = s; dst32[e] = d;
}

__global__ __launch_bounds__(256) void k_count(const int* __restrict__ dst32, int* __restrict__ deg){
  int e = blockIdx.x*256 + threadIdx.x;
  if (e < NE) atomicAdd(&deg[dst32[e]], 1);
}

// ---- exclusive scan of deg -> rowptr (3-kernel, chunk=1024) ----
__global__ __launch_bounds__(1024) void k_scan1(const int* __restrict__ deg, int* __restrict__ rowptr, int* __restrict__ sums){
  __shared__ int sh[1024];
  int t = threadIdx.x; int i = blockIdx.x*1024 + t;
  sh[t] = (i < NN) ? deg[i] : 0;
  __syncthreads();
  for (int off = 1; off < 1024; off <<= 1){
    int add = (t >= off) ? sh[t-off] : 0;
    __syncthreads();
    sh[t] += add;
    __syncthreads();
  }
  if (i < NN) rowptr[i+1] = sh[t];
  if (t == 1023) sums[blockIdx.x] = sh[1023];
}

__global__ void k_scan2(int* sums, int nchunks){
  if (threadIdx.x == 0 && blockIdx.x == 0){
    int acc = 0;
    for (int i = 0; i < nchunks; i++){ int v = sums[i]; sums[i] = acc; acc += v; }
  }
}

__global__ __launch_bounds__(256) void k_scan3(int* __restrict__ rowptr, const int* __restrict__ sums){
  int i = blockIdx.x*256 + threadIdx.x;
  if (i < NN) rowptr[i+1] += sums[i >> 10];
  if (i == 0) rowptr[0] = 0;
}

__global__ __launch_bounds__(256) void k_fill(const int* __restrict__ src32, const int* __restrict__ dst32,
                                              const int* __restrict__ rowptr, int* __restrict__ fill,
                                              int* __restrict__ colsrc){
  int e = blockIdx.x*256 + threadIdx.x;
  if (e >= NE) return;
  int d = dst32[e];
  int pos = rowptr[d] + atomicAdd(&fill[d], 1);
  colsrc[pos] = src32[e];
}

// ---- layer1 GEMM: h1[N,256] = x @ W1^T, fused per-node attention dots ----
__global__ __launch_bounds__(256) void k_gemm1(const float* __restrict__ x, const float* __restrict__ W1,
    const float* __restrict__ atts, const float* __restrict__ attd,
    float* __restrict__ h1, float* __restrict__ as1, float* __restrict__ ad1){
  __shared__ float xs[8*INC];
  int tid = threadIdx.x;
  int n0 = blockIdx.x*8;
  ((float4*)xs)[tid] = ((const float4*)(x + (size_t)n0*INC))[tid];
  __syncthreads();
  int col = tid;
  const float4* w4 = (const float4*)(W1 + (size_t)col*INC);
  float acc[8];
  #pragma unroll
  for (int i = 0; i < 8; i++) acc[i] = 0.f;
  #pragma unroll 8
  for (int k4 = 0; k4 < INC/4; k4++){
    float4 wv = w4[k4];
    #pragma unroll
    for (int i = 0; i < 8; i++){
      float4 xv = ((const float4*)xs)[i*(INC/4) + k4];
      acc[i] += wv.x*xv.x + wv.y*xv.y + wv.z*xv.z + wv.w*xv.w;
    }
  }
  float av_s = atts[col], av_d = attd[col];
  int head = tid >> 6;
  #pragma unroll
  for (int i = 0; i < 8; i++){
    h1[((size_t)(n0+i))*HIDC + col] = acc[i];
    float ps = acc[i]*av_s, pd = acc[i]*av_d;
    #pragma unroll
    for (int off = 32; off > 0; off >>= 1){ ps += __shfl_down(ps, off); pd += __shfl_down(pd, off); }
    if ((tid & 63) == 0){ as1[(n0+i)*NH + head] = ps; ad1[(n0+i)*NH + head] = pd; }
  }
}

// ---- layer1 aggregation: fused softmax-weighted mean + bias + ELU ----
__global__ __launch_bounds__(256) void k_agg1(const float* __restrict__ h1, const float* __restrict__ as1,
    const float* __restrict__ ad1, const int* __restrict__ rowptr, const int* __restrict__ colsrc,
    const float* __restrict__ b1, float* __restrict__ h1a){
  int n = blockIdx.x; int tid = threadIdx.x; int head = tid >> 6;
  float adn = ad1[n*NH + head];
  float l = lrelu(as1[n*NH + head] + adn);
  float e = __expf(l);
  float den = 1e-16f + e;
  float acc = e * h1[(size_t)n*HIDC + tid];
  int beg = rowptr[n], end = rowptr[n+1];
  for (int j = beg; j < end; j++){
    int s = colsrc[j];
    float es = __expf(lrelu(as1[s*NH + head] + adn));
    acc += es * h1[(size_t)s*HIDC + tid];
    den += es;
  }
  float o = acc/den + b1[tid];
  h1a[(size_t)n*HIDC + tid] = o > 0.f ? o : (__expf(o) - 1.f);
}

// ---- layer2 GEMM: h2[N,40] = h1a @ W2^T, fused attention dots ----
__global__ __launch_bounds__(320) void k_gemm2(const float* __restrict__ h1a, const float* __restrict__ W2,
    const float* __restrict__ atts2, const float* __restrict__ attd2,
    float* __restrict__ h2, float* __restrict__ a2s, float* __restrict__ a2d){
  __shared__ float xs[8*HIDC];
  __shared__ float rs[8], rd[8];
  int tid = threadIdx.x;
  int n0 = blockIdx.x*8;
  if (tid < 8){ rs[tid] = 0.f; rd[tid] = 0.f; }
  for (int i = tid; i < 8*HIDC/4; i += 320)
    ((float4*)xs)[i] = ((const float4*)(h1a + (size_t)n0*HIDC))[i];
  __syncthreads();
  int node = tid/40, col = tid%40;
  const float4* w4 = (const float4*)(W2 + (size_t)col*HIDC);
  const float4* x4 = (const float4*)(xs + node*HIDC);
  float acc = 0.f;
  #pragma unroll 8
  for (int k = 0; k < HIDC/4; k++){
    float4 wv = w4[k], xv = x4[k];
    acc += wv.x*xv.x + wv.y*xv.y + wv.z*xv.z + wv.w*xv.w;
  }
  h2[(size_t)(n0+node)*OUTC + col] = acc;
  atomicAdd(&rs[node], acc*atts2[col]);
  atomicAdd(&rd[node], acc*attd2[col]);
  __syncthreads();
  if (col == 0){ a2s[n0+node] = rs[node]; a2d[n0+node] = rd[node]; }
}

// ---- layer2 aggregation: softmax-weighted mean + bias -> out ----
__global__ __launch_bounds__(64) void k_agg2(const float* __restrict__ h2, const float* __restrict__ a2s,
    const float* __restrict__ a2d, const int* __restrict__ rowptr, const int* __restrict__ colsrc,
    const float* __restrict__ b2, float* __restrict__ out){
  int n = blockIdx.x; int tid = threadIdx.x;
  float adn = a2d[n];
  float e = __expf(lrelu(a2s[n] + adn));
  float den = 1e-16f + e;
  float acc = (tid < OUTC) ? e * h2[(size_t)n*OUTC + tid] : 0.f;
  int beg = rowptr[n], end = rowptr[n+1];
  for (int j = beg; j < end; j++){
    int s = colsrc[j];
    float es = __expf(lrelu(a2s[s] + adn));
    if (tid < OUTC) acc += es * h2[(size_t)s*OUTC + tid];
    den += es;
  }
  if (tid < OUTC) out[(size_t)n*OUTC + tid] = acc/den + b2[tid];
}

extern "C" void kernel_launch(void* const* d_in, const int* in_sizes, int n_in,
                              void* d_out, int out_size, void* d_ws, size_t ws_size,
                              hipStream_t stream){
  const float* x    = (const float*)d_in[0];
  const void*  ei   = d_in[1];
  const float* W1   = (const float*)d_in[2];
  const float* as1w = (const float*)d_in[3];
  const float* ad1w = (const float*)d_in[4];
  const float* b1   = (const float*)d_in[5];
  const float* W2   = (const float*)d_in[6];
  const float* as2w = (const float*)d_in[7];
  const float* ad2w = (const float*)d_in[8];
  const float* b2   = (const float*)d_in[9];
  float* out = (float*)d_out;

  char* base = (char*)d_ws;
  size_t off = 0;
  auto alloc = [&](size_t bytes)->char*{ char* r = base + off; off += (bytes + 255) & ~(size_t)255; return r; };
  int* flag   = (int*)alloc(sizeof(int));
  int* src32  = (int*)alloc((size_t)NE*sizeof(int));
  int* dst32  = (int*)alloc((size_t)NE*sizeof(int));
  int* deg    = (int*)alloc((size_t)NN*sizeof(int));
  int* rowptr = (int*)alloc((size_t)(NN+1)*sizeof(int));
  int* fillc  = (int*)alloc((size_t)NN*sizeof(int));
  int* sums   = (int*)alloc(64*sizeof(int));
  int* colsrc = (int*)alloc((size_t)NE*sizeof(int));
  float* h1   = (float*)alloc((size_t)NN*HIDC*sizeof(float));
  float* h1a  = (float*)alloc((size_t)NN*HIDC*sizeof(float));
  float* as1  = (float*)alloc((size_t)NN*NH*sizeof(float));
  float* ad1  = (float*)alloc((size_t)NN*NH*sizeof(float));
  float* h2   = (float*)alloc((size_t)NN*OUTC*sizeof(float));
  float* a2s  = (float*)alloc((size_t)NN*sizeof(float));
  float* a2d  = (float*)alloc((size_t)NN*sizeof(float));

  hipMemsetAsync(deg,   0, (size_t)NN*sizeof(int), stream);
  hipMemsetAsync(fillc, 0, (size_t)NN*sizeof(int), stream);

  int gE = (NE + 255)/256;
  int nchunks = (NN + 1023)/1024;
  k_detect<<<1, 64, 0, stream>>>((const long long*)ei, flag);
  k_convert<<<gE, 256, 0, stream>>>(ei, flag, src32, dst32);
  k_count<<<gE, 256, 0, stream>>>(dst32, deg);
  k_scan1<<<nchunks, 1024, 0, stream>>>(deg, rowptr, sums);
  k_scan2<<<1, 64, 0, stream>>>(sums, nchunks);
  k_scan3<<<(NN + 255)/256, 256, 0, stream>>>(rowptr, sums);
  k_fill<<<gE, 256, 0, stream>>>(src32, dst32, rowptr, fillc, colsrc);
  k_gemm1<<<NN/8, 256, 0, stream>>>(x, W1, as1w, ad1w, h1, as1, ad1);
  k_agg1<<<NN, 256, 0, stream>>>(h1, as1, ad1, rowptr, colsrc, b1, h1a);
  k_gemm2<<<NN/8, 320, 0, stream>>>(h1a, W2, as2w, ad2w, h2, a2s, a2d);
  k_agg2<<<NN, 64, 0, stream>>>(h2, a2s, a2d, rowptr, colsrc, b2, out);
}

// Round 2
// 508.671 us; speedup vs baseline: 1.3872x; 1.3872x over previous
//
#include <hip/hip_runtime.h>
#include <cstdint>
#include <cstddef>

#define NN 50000
#define NE 800000
#define INC 128
#define HIDC 256
#define NH 4
#define OUTC 40

__device__ __forceinline__ float lrelu(float x){ return x > 0.f ? x : 0.2f*x; }

// ---- edge dtype detection: int64 view of int32 pairs gives values >= 2^32 ----
__global__ __launch_bounds__(64) void k_detect(const long long* __restrict__ ei, int* __restrict__ flag){
  int t = threadIdx.x;
  long long v = ei[(long long)t * (NE/64)];
  bool ok = (v >= 0) && (v < NN);
  unsigned long long m = __ballot(ok);
  if (t == 0) *flag = (m == 0xFFFFFFFFFFFFFFFFull) ? 1 : 0;
}

__global__ __launch_bounds__(256) void k_convert(const void* __restrict__ ei, const int* __restrict__ flag,
                                                 int* __restrict__ src32, int* __restrict__ dst32){
  int e = blockIdx.x*256 + threadIdx.x;
  if (e >= NE) return;
  int s, d;
  if (*flag){
    const long long* p = (const long long*)ei;
    s = (int)p[e]; d = (int)p[NE+e];
  } else {
    const int* p = (const int*)ei;
    s = p[e]; d = p[NE+e];
  }
  s = min(max(s,0),NN-1); d = min(max(d,0),NN-1);
  src32[e] = s; dst32[e] = d;
}

__global__ __launch_bounds__(256) void k_count(const int* __restrict__ dst32, int* __restrict__ deg){
  int e = blockIdx.x*256 + threadIdx.x;
  if (e < NE) atomicAdd(&deg[dst32[e]], 1);
}

// ---- exclusive scan of deg -> rowptr (3-kernel, chunk=1024) ----
__global__ __launch_bounds__(1024) void k_scan1(const int* __restrict__ deg, int* __restrict__ rowptr, int* __restrict__ sums){
  __shared__ int sh[1024];
  int t = threadIdx.x; int i = blockIdx.x*1024 + t;
  sh[t] = (i < NN) ? deg[i] : 0;
  __syncthreads();
  for (int off = 1; off < 1024; off <<= 1){
    int add = (t >= off) ? sh[t-off] : 0;
    __syncthreads();
    sh[t] += add;
    __syncthreads();
  }
  if (i < NN) rowptr[i+1] = sh[t];
  if (t == 1023) sums[blockIdx.x] = sh[1023];
}

__global__ void k_scan2(int* sums, int nchunks){
  if (threadIdx.x == 0 && blockIdx.x == 0){
    int acc = 0;
    for (int i = 0; i < nchunks; i++){ int v = sums[i]; sums[i] = acc; acc += v; }
  }
}

__global__ __launch_bounds__(256) void k_scan3(int* __restrict__ rowptr, const int* __restrict__ sums){
  int i = blockIdx.x*256 + threadIdx.x;
  if (i < NN) rowptr[i+1] += sums[i >> 10];
  if (i == 0) rowptr[0] = 0;
}

__global__ __launch_bounds__(256) void k_fill(const int* __restrict__ src32, const int* __restrict__ dst32,
                                              const int* __restrict__ rowptr, int* __restrict__ fill,
                                              int* __restrict__ colsrc){
  int e = blockIdx.x*256 + threadIdx.x;
  if (e >= NE) return;
  int d = dst32[e];
  int pos = rowptr[d] + atomicAdd(&fill[d], 1);
  colsrc[pos] = src32[e];
}

// ---- layer1 GEMM: h1[N,256] = x @ W1^T, fused per-node attention dots ----
__global__ __launch_bounds__(256) void k_gemm1(const float* __restrict__ x, const float* __restrict__ W1,
    const float* __restrict__ atts, const float* __restrict__ attd,
    float* __restrict__ h1, float* __restrict__ as1, float* __restrict__ ad1){
  __shared__ float xs[8*INC];
  int tid = threadIdx.x;
  int n0 = blockIdx.x*8;
  ((float4*)xs)[tid] = ((const float4*)(x + (size_t)n0*INC))[tid];
  __syncthreads();
  int col = tid;
  const float4* w4 = (const float4*)(W1 + (size_t)col*INC);
  float acc[8];
  #pragma unroll
  for (int i = 0; i < 8; i++) acc[i] = 0.f;
  #pragma unroll 8
  for (int k4 = 0; k4 < INC/4; k4++){
    float4 wv = w4[k4];
    #pragma unroll
    for (int i = 0; i < 8; i++){
      float4 xv = ((const float4*)xs)[i*(INC/4) + k4];
      acc[i] += wv.x*xv.x + wv.y*xv.y + wv.z*xv.z + wv.w*xv.w;
    }
  }
  float av_s = atts[col], av_d = attd[col];
  int head = tid >> 6;
  #pragma unroll
  for (int i = 0; i < 8; i++){
    h1[((size_t)(n0+i))*HIDC + col] = acc[i];
    float ps = acc[i]*av_s, pd = acc[i]*av_d;
    #pragma unroll
    for (int off = 32; off > 0; off >>= 1){ ps += __shfl_down(ps, off); pd += __shfl_down(pd, off); }
    if ((tid & 63) == 0){ as1[(n0+i)*NH + head] = ps; ad1[(n0+i)*NH + head] = pd; }
  }
}

// ---- layer1 aggregation: fused softmax-weighted mean + bias + ELU ----
__global__ __launch_bounds__(256) void k_agg1(const float* __restrict__ h1, const float* __restrict__ as1,
    const float* __restrict__ ad1, const int* __restrict__ rowptr, const int* __restrict__ colsrc,
    const float* __restrict__ b1, float* __restrict__ h1a){
  int n = blockIdx.x; int tid = threadIdx.x; int head = tid >> 6;
  float adn = ad1[n*NH + head];
  float l = lrelu(as1[n*NH + head] + adn);
  float e = __expf(l);
  float den = 1e-16f + e;
  float acc = e * h1[(size_t)n*HIDC + tid];
  int beg = rowptr[n], end = rowptr[n+1];
  for (int j = beg; j < end; j++){
    int s = colsrc[j];
    float es = __expf(lrelu(as1[s*NH + head] + adn));
    acc += es * h1[(size_t)s*HIDC + tid];
    den += es;
  }
  float o = acc/den + b1[tid];
  h1a[(size_t)n*HIDC + tid] = o > 0.f ? o : (__expf(o) - 1.f);
}

// ---- layer2 GEMM (rewritten): one node per thread, W2^T staged in LDS,
//      broadcast b128 reads, 40 VGPR accumulators, thread-local attention dots ----
__global__ __launch_bounds__(256) void k_gemm2(const float* __restrict__ h1a, const float* __restrict__ W2,
    const float* __restrict__ atts2, const float* __restrict__ attd2,
    float* __restrict__ h2, float* __restrict__ a2s, float* __restrict__ a2d){
  __shared__ float W2t[HIDC*OUTC];   // [k][c] transposed, 40 KB
  __shared__ float sA[OUTC], sD[OUTC];
  int tid = threadIdx.x;
  // stage + transpose W2: read coalesced, scatter to LDS (one-time)
  #pragma unroll
  for (int it = 0; it < (OUTC*HIDC)/256; it++){
    int idx = it*256 + tid;
    int c = idx >> 8, k = idx & 255;
    W2t[k*OUTC + c] = W2[idx];
  }
  if (tid < OUTC){ sA[tid] = atts2[tid]; sD[tid] = attd2[tid]; }
  __syncthreads();

  int n = blockIdx.x*256 + tid;
  if (n >= NN) return;

  float acc[OUTC];
  #pragma unroll
  for (int c = 0; c < OUTC; c++) acc[c] = 0.f;

  const float4* x4p = (const float4*)(h1a + (size_t)n*HIDC);
  const float4* w4p = (const float4*)W2t;
  #pragma unroll 2
  for (int k4 = 0; k4 < HIDC/4; k4++){
    float4 xv = x4p[k4];
    #pragma unroll
    for (int kk = 0; kk < 4; kk++){
      float xk = (kk==0) ? xv.x : (kk==1) ? xv.y : (kk==2) ? xv.z : xv.w;
      #pragma unroll
      for (int c4 = 0; c4 < OUTC/4; c4++){
        float4 wv = w4p[(k4*4 + kk)*(OUTC/4) + c4];  // same addr all lanes: broadcast
        acc[c4*4+0] += xk*wv.x;
        acc[c4*4+1] += xk*wv.y;
        acc[c4*4+2] += xk*wv.z;
        acc[c4*4+3] += xk*wv.w;
      }
    }
  }

  float s2 = 0.f, d2 = 0.f;
  #pragma unroll
  for (int c = 0; c < OUTC; c++){ s2 += acc[c]*sA[c]; d2 += acc[c]*sD[c]; }

  float* h2row = h2 + (size_t)n*OUTC;
  #pragma unroll
  for (int c4 = 0; c4 < OUTC/4; c4++){
    float4 v; v.x = acc[c4*4+0]; v.y = acc[c4*4+1]; v.z = acc[c4*4+2]; v.w = acc[c4*4+3];
    ((float4*)h2row)[c4] = v;
  }
  a2s[n] = s2; a2d[n] = d2;
}

// ---- layer2 aggregation: softmax-weighted mean + bias -> out ----
__global__ __launch_bounds__(64) void k_agg2(const float* __restrict__ h2, const float* __restrict__ a2s,
    const float* __restrict__ a2d, const int* __restrict__ rowptr, const int* __restrict__ colsrc,
    const float* __restrict__ b2, float* __restrict__ out){
  int n = blockIdx.x; int tid = threadIdx.x;
  float adn = a2d[n];
  float e = __expf(lrelu(a2s[n] + adn));
  float den = 1e-16f + e;
  float acc = (tid < OUTC) ? e * h2[(size_t)n*OUTC + tid] : 0.f;
  int beg = rowptr[n], end = rowptr[n+1];
  for (int j = beg; j < end; j++){
    int s = colsrc[j];
    float es = __expf(lrelu(a2s[s] + adn));
    if (tid < OUTC) acc += es * h2[(size_t)s*OUTC + tid];
    den += es;
  }
  if (tid < OUTC) out[(size_t)n*OUTC + tid] = acc/den + b2[tid];
}

extern "C" void kernel_launch(void* const* d_in, const int* in_sizes, int n_in,
                              void* d_out, int out_size, void* d_ws, size_t ws_size,
                              hipStream_t stream){
  const float* x    = (const float*)d_in[0];
  const void*  ei   = d_in[1];
  const float* W1   = (const float*)d_in[2];
  const float* as1w = (const float*)d_in[3];
  const float* ad1w = (const float*)d_in[4];
  const float* b1   = (const float*)d_in[5];
  const float* W2   = (const float*)d_in[6];
  const float* as2w = (const float*)d_in[7];
  const float* ad2w = (const float*)d_in[8];
  const float* b2   = (const float*)d_in[9];
  float* out = (float*)d_out;

  char* base = (char*)d_ws;
  size_t off = 0;
  auto alloc = [&](size_t bytes)->char*{ char* r = base + off; off += (bytes + 255) & ~(size_t)255; return r; };
  int* flag   = (int*)alloc(sizeof(int));
  int* src32  = (int*)alloc((size_t)NE*sizeof(int));
  int* dst32  = (int*)alloc((size_t)NE*sizeof(int));
  int* deg    = (int*)alloc((size_t)NN*sizeof(int));
  int* rowptr = (int*)alloc((size_t)(NN+1)*sizeof(int));
  int* fillc  = (int*)alloc((size_t)NN*sizeof(int));
  int* sums   = (int*)alloc(64*sizeof(int));
  int* colsrc = (int*)alloc((size_t)NE*sizeof(int));
  float* h1   = (float*)alloc((size_t)NN*HIDC*sizeof(float));
  float* h1a  = (float*)alloc((size_t)NN*HIDC*sizeof(float));
  float* as1  = (float*)alloc((size_t)NN*NH*sizeof(float));
  float* ad1  = (float*)alloc((size_t)NN*NH*sizeof(float));
  float* h2   = (float*)alloc((size_t)NN*OUTC*sizeof(float));
  float* a2s  = (float*)alloc((size_t)NN*sizeof(float));
  float* a2d  = (float*)alloc((size_t)NN*sizeof(float));

  hipMemsetAsync(deg,   0, (size_t)NN*sizeof(int), stream);
  hipMemsetAsync(fillc, 0, (size_t)NN*sizeof(int), stream);

  int gE = (NE + 255)/256;
  int nchunks = (NN + 1023)/1024;
  k_detect<<<1, 64, 0, stream>>>((const long long*)ei, flag);
  k_convert<<<gE, 256, 0, stream>>>(ei, flag, src32, dst32);
  k_count<<<gE, 256, 0, stream>>>(dst32, deg);
  k_scan1<<<nchunks, 1024, 0, stream>>>(deg, rowptr, sums);
  k_scan2<<<1, 64, 0, stream>>>(sums, nchunks);
  k_scan3<<<(NN + 255)/256, 256, 0, stream>>>(rowptr, sums);
  k_fill<<<gE, 256, 0, stream>>>(src32, dst32, rowptr, fillc, colsrc);
  k_gemm1<<<NN/8, 256, 0, stream>>>(x, W1, as1w, ad1w, h1, as1, ad1);
  k_agg1<<<NN, 256, 0, stream>>>(h1, as1, ad1, rowptr, colsrc, b1, h1a);
  k_gemm2<<<(NN + 255)/256, 256, 0, stream>>>(h1a, W2, as2w, ad2w, h2, a2s, a2d);
  k_agg2<<<NN, 64, 0, stream>>>(h2, a2s, a2d, rowptr, colsrc, b2, out);
}

// Round 3
// 407.259 us; speedup vs baseline: 1.7326x; 1.2490x over previous
//
#include <hip/hip_runtime.h>
#include <hip/hip_bf16.h>
#include <cstdint>
#include <cstddef>

#define NN 50000
#define NE 800000
#define INC 128
#define HIDC 256
#define NH 4
#define OUTC 40

__device__ __forceinline__ float lrelu(float x){ return x > 0.f ? x : 0.2f*x; }

// ---- edge dtype detection: int64 view of int32 pairs gives values >= 2^32 ----
__global__ __launch_bounds__(64) void k_detect(const long long* __restrict__ ei, int* __restrict__ flag){
  int t = threadIdx.x;
  long long v = ei[(long long)t * (NE/64)];
  bool ok = (v >= 0) && (v < NN);
  unsigned long long m = __ballot(ok);
  if (t == 0) *flag = (m == 0xFFFFFFFFFFFFFFFFull) ? 1 : 0;
}

__global__ __launch_bounds__(256) void k_convert(const void* __restrict__ ei, const int* __restrict__ flag,
                                                 int* __restrict__ src32, int* __restrict__ dst32){
  int e = blockIdx.x*256 + threadIdx.x;
  if (e >= NE) return;
  int s, d;
  if (*flag){
    const long long* p = (const long long*)ei;
    s = (int)p[e]; d = (int)p[NE+e];
  } else {
    const int* p = (const int*)ei;
    s = p[e]; d = p[NE+e];
  }
  s = min(max(s,0),NN-1); d = min(max(d,0),NN-1);
  src32[e] = s; dst32[e] = d;
}

__global__ __launch_bounds__(256) void k_count(const int* __restrict__ dst32, int* __restrict__ deg){
  int e = blockIdx.x*256 + threadIdx.x;
  if (e < NE) atomicAdd(&deg[dst32[e]], 1);
}

// ---- exclusive scan of deg -> rowptr (3-kernel, chunk=1024) ----
__global__ __launch_bounds__(1024) void k_scan1(const int* __restrict__ deg, int* __restrict__ rowptr, int* __restrict__ sums){
  __shared__ int sh[1024];
  int t = threadIdx.x; int i = blockIdx.x*1024 + t;
  sh[t] = (i < NN) ? deg[i] : 0;
  __syncthreads();
  for (int off = 1; off < 1024; off <<= 1){
    int add = (t >= off) ? sh[t-off] : 0;
    __syncthreads();
    sh[t] += add;
    __syncthreads();
  }
  if (i < NN) rowptr[i+1] = sh[t];
  if (t == 1023) sums[blockIdx.x] = sh[1023];
}

__global__ void k_scan2(int* sums, int nchunks){
  if (threadIdx.x == 0 && blockIdx.x == 0){
    int acc = 0;
    for (int i = 0; i < nchunks; i++){ int v = sums[i]; sums[i] = acc; acc += v; }
  }
}

__global__ __launch_bounds__(256) void k_scan3(int* __restrict__ rowptr, const int* __restrict__ sums){
  int i = blockIdx.x*256 + threadIdx.x;
  if (i < NN) rowptr[i+1] += sums[i >> 10];
  if (i == 0) rowptr[0] = 0;
}

__global__ __launch_bounds__(256) void k_fill(const int* __restrict__ src32, const int* __restrict__ dst32,
                                              const int* __restrict__ rowptr, int* __restrict__ fill,
                                              int* __restrict__ colsrc, int* __restrict__ epos){
  int e = blockIdx.x*256 + threadIdx.x;
  if (e >= NE) return;
  int d = dst32[e];
  int pos = rowptr[d] + atomicAdd(&fill[d], 1);
  colsrc[pos] = src32[e];
  epos[e] = pos;
}

// ---- layer1 GEMM: h1[N,256] = x @ W1^T (stored bf16), fused attention dots ----
__global__ __launch_bounds__(256) void k_gemm1(const float* __restrict__ x, const float* __restrict__ W1,
    const float* __restrict__ atts, const float* __restrict__ attd,
    __hip_bfloat16* __restrict__ h1b, float* __restrict__ as1, float* __restrict__ ad1){
  __shared__ float xs[8*INC];
  int tid = threadIdx.x;
  int n0 = blockIdx.x*8;
  ((float4*)xs)[tid] = ((const float4*)(x + (size_t)n0*INC))[tid];
  __syncthreads();
  int col = tid;
  const float4* w4 = (const float4*)(W1 + (size_t)col*INC);
  float acc[8];
  #pragma unroll
  for (int i = 0; i < 8; i++) acc[i] = 0.f;
  #pragma unroll 8
  for (int k4 = 0; k4 < INC/4; k4++){
    float4 wv = w4[k4];
    #pragma unroll
    for (int i = 0; i < 8; i++){
      float4 xv = ((const float4*)xs)[i*(INC/4) + k4];
      acc[i] += wv.x*xv.x + wv.y*xv.y + wv.z*xv.z + wv.w*xv.w;
    }
  }
  float av_s = atts[col], av_d = attd[col];
  int head = tid >> 6;
  #pragma unroll
  for (int i = 0; i < 8; i++){
    h1b[((size_t)(n0+i))*HIDC + col] = __float2bfloat16(acc[i]);
    float ps = acc[i]*av_s, pd = acc[i]*av_d;
    #pragma unroll
    for (int off = 32; off > 0; off >>= 1){ ps += __shfl_down(ps, off); pd += __shfl_down(pd, off); }
    if ((tid & 63) == 0){ as1[(n0+i)*NH + head] = ps; ad1[(n0+i)*NH + head] = pd; }
  }
}

// ---- per-edge attention weights for layer1: es4[pos] = exp(lrelu(as1[s]+ad1[d])) per head ----
__global__ __launch_bounds__(256) void k_es(const int* __restrict__ src32, const int* __restrict__ dst32,
    const int* __restrict__ epos, const float* __restrict__ as1, const float* __restrict__ ad1,
    float4* __restrict__ es4){
  int e = blockIdx.x*256 + threadIdx.x;
  if (e >= NE) return;
  int s = src32[e], d = dst32[e];
  float4 vs = ((const float4*)as1)[s];
  float4 vd = ((const float4*)ad1)[d];
  float4 r;
  r.x = __expf(lrelu(vs.x + vd.x));
  r.y = __expf(lrelu(vs.y + vd.y));
  r.z = __expf(lrelu(vs.z + vd.z));
  r.w = __expf(lrelu(vs.w + vd.w));
  es4[epos[e]] = r;
}

// ---- layer1 aggregation: bf16 gather, precomputed es, 2 ch/thread, unroll-2 ----
__global__ __launch_bounds__(128) void k_agg1(const __hip_bfloat16* __restrict__ h1b,
    const float4* __restrict__ es4, const float* __restrict__ as1, const float* __restrict__ ad1,
    const int* __restrict__ rowptr, const int* __restrict__ colsrc,
    const float* __restrict__ b1, float* __restrict__ h1a){
  int n = blockIdx.x; int tid = threadIdx.x; int head = tid >> 5;
  const unsigned* h1u = (const unsigned*)h1b;

  // self-loop term
  float es_self = __expf(lrelu(as1[n*NH + head] + ad1[n*NH + head]));
  float den = 1e-16f + es_self;
  unsigned v = h1u[(size_t)n*(HIDC/2) + tid];
  float a0 = es_self * __uint_as_float(v << 16);
  float a1 = es_self * __uint_as_float(v & 0xffff0000u);

  int beg = rowptr[n], end = rowptr[n+1];
  int j = beg;
  for (; j + 1 < end; j += 2){
    int s0 = colsrc[j], s1 = colsrc[j+1];
    float4 e0 = es4[j], e1 = es4[j+1];
    unsigned v0 = h1u[(size_t)s0*(HIDC/2) + tid];
    unsigned v1 = h1u[(size_t)s1*(HIDC/2) + tid];
    float w0 = (head & 2) ? ((head & 1) ? e0.w : e0.z) : ((head & 1) ? e0.y : e0.x);
    float w1 = (head & 2) ? ((head & 1) ? e1.w : e1.z) : ((head & 1) ? e1.y : e1.x);
    den += w0 + w1;
    a0 += w0 * __uint_as_float(v0 << 16);
    a1 += w0 * __uint_as_float(v0 & 0xffff0000u);
    a0 += w1 * __uint_as_float(v1 << 16);
    a1 += w1 * __uint_as_float(v1 & 0xffff0000u);
  }
  if (j < end){
    int s0 = colsrc[j];
    float4 e0 = es4[j];
    unsigned v0 = h1u[(size_t)s0*(HIDC/2) + tid];
    float w0 = (head & 2) ? ((head & 1) ? e0.w : e0.z) : ((head & 1) ? e0.y : e0.x);
    den += w0;
    a0 += w0 * __uint_as_float(v0 << 16);
    a1 += w0 * __uint_as_float(v0 & 0xffff0000u);
  }

  float2 bb = ((const float2*)b1)[tid];
  float rinv = 1.f / den;
  float o0 = a0*rinv + bb.x;
  float o1 = a1*rinv + bb.y;
  o0 = o0 > 0.f ? o0 : (__expf(o0) - 1.f);
  o1 = o1 > 0.f ? o1 : (__expf(o1) - 1.f);
  ((float2*)(h1a + (size_t)n*HIDC))[tid] = make_float2(o0, o1);
}

// ---- layer2 GEMM: one node per thread, W2^T staged in LDS ----
__global__ __launch_bounds__(256) void k_gemm2(const float* __restrict__ h1a, const float* __restrict__ W2,
    const float* __restrict__ atts2, const float* __restrict__ attd2,
    float* __restrict__ h2, float* __restrict__ a2s, float* __restrict__ a2d){
  __shared__ float W2t[HIDC*OUTC];   // [k][c] transposed, 40 KB
  __shared__ float sA[OUTC], sD[OUTC];
  int tid = threadIdx.x;
  #pragma unroll
  for (int it = 0; it < (OUTC*HIDC)/256; it++){
    int idx = it*256 + tid;
    int c = idx >> 8, k = idx & 255;
    W2t[k*OUTC + c] = W2[idx];
  }
  if (tid < OUTC){ sA[tid] = atts2[tid]; sD[tid] = attd2[tid]; }
  __syncthreads();

  int n = blockIdx.x*256 + tid;
  if (n >= NN) return;

  float acc[OUTC];
  #pragma unroll
  for (int c = 0; c < OUTC; c++) acc[c] = 0.f;

  const float4* x4p = (const float4*)(h1a + (size_t)n*HIDC);
  const float4* w4p = (const float4*)W2t;
  #pragma unroll 2
  for (int k4 = 0; k4 < HIDC/4; k4++){
    float4 xv = x4p[k4];
    #pragma unroll
    for (int kk = 0; kk < 4; kk++){
      float xk = (kk==0) ? xv.x : (kk==1) ? xv.y : (kk==2) ? xv.z : xv.w;
      #pragma unroll
      for (int c4 = 0; c4 < OUTC/4; c4++){
        float4 wv = w4p[(k4*4 + kk)*(OUTC/4) + c4];
        acc[c4*4+0] += xk*wv.x;
        acc[c4*4+1] += xk*wv.y;
        acc[c4*4+2] += xk*wv.z;
        acc[c4*4+3] += xk*wv.w;
      }
    }
  }

  float s2 = 0.f, d2 = 0.f;
  #pragma unroll
  for (int c = 0; c < OUTC; c++){ s2 += acc[c]*sA[c]; d2 += acc[c]*sD[c]; }

  float* h2row = h2 + (size_t)n*OUTC;
  #pragma unroll
  for (int c4 = 0; c4 < OUTC/4; c4++){
    float4 v; v.x = acc[c4*4+0]; v.y = acc[c4*4+1]; v.z = acc[c4*4+2]; v.w = acc[c4*4+3];
    ((float4*)h2row)[c4] = v;
  }
  a2s[n] = s2; a2d[n] = d2;
}

// ---- layer2 aggregation: softmax-weighted mean + bias -> out ----
__global__ __launch_bounds__(64) void k_agg2(const float* __restrict__ h2, const float* __restrict__ a2s,
    const float* __restrict__ a2d, const int* __restrict__ rowptr, const int* __restrict__ colsrc,
    const float* __restrict__ b2, float* __restrict__ out){
  int n = blockIdx.x; int tid = threadIdx.x;
  float adn = a2d[n];
  float e = __expf(lrelu(a2s[n] + adn));
  float den = 1e-16f + e;
  float acc = (tid < OUTC) ? e * h2[(size_t)n*OUTC + tid] : 0.f;
  int beg = rowptr[n], end = rowptr[n+1];
  for (int j = beg; j < end; j++){
    int s = colsrc[j];
    float es = __expf(lrelu(a2s[s] + adn));
    if (tid < OUTC) acc += es * h2[(size_t)s*OUTC + tid];
    den += es;
  }
  if (tid < OUTC) out[(size_t)n*OUTC + tid] = acc/den + b2[tid];
}

extern "C" void kernel_launch(void* const* d_in, const int* in_sizes, int n_in,
                              void* d_out, int out_size, void* d_ws, size_t ws_size,
                              hipStream_t stream){
  const float* x    = (const float*)d_in[0];
  const void*  ei   = d_in[1];
  const float* W1   = (const float*)d_in[2];
  const float* as1w = (const float*)d_in[3];
  const float* ad1w = (const float*)d_in[4];
  const float* b1   = (const float*)d_in[5];
  const float* W2   = (const float*)d_in[6];
  const float* as2w = (const float*)d_in[7];
  const float* ad2w = (const float*)d_in[8];
  const float* b2   = (const float*)d_in[9];
  float* out = (float*)d_out;

  char* base = (char*)d_ws;
  size_t off = 0;
  auto alloc = [&](size_t bytes)->char*{ char* r = base + off; off += (bytes + 255) & ~(size_t)255; return r; };
  int* flag   = (int*)alloc(sizeof(int));
  int* src32  = (int*)alloc((size_t)NE*sizeof(int));
  int* dst32  = (int*)alloc((size_t)NE*sizeof(int));
  int* deg    = (int*)alloc((size_t)NN*sizeof(int));
  int* rowptr = (int*)alloc((size_t)(NN+1)*sizeof(int));
  int* fillc  = (int*)alloc((size_t)NN*sizeof(int));
  int* sums   = (int*)alloc(64*sizeof(int));
  int* colsrc = (int*)alloc((size_t)NE*sizeof(int));
  int* epos   = (int*)alloc((size_t)NE*sizeof(int));
  float4* es4 = (float4*)alloc((size_t)NE*sizeof(float4));
  __hip_bfloat16* h1b = (__hip_bfloat16*)alloc((size_t)NN*HIDC*sizeof(__hip_bfloat16));
  float* h1a  = (float*)alloc((size_t)NN*HIDC*sizeof(float));
  float* as1  = (float*)alloc((size_t)NN*NH*sizeof(float));
  float* ad1  = (float*)alloc((size_t)NN*NH*sizeof(float));
  float* h2   = (float*)alloc((size_t)NN*OUTC*sizeof(float));
  float* a2s  = (float*)alloc((size_t)NN*sizeof(float));
  float* a2d  = (float*)alloc((size_t)NN*sizeof(float));

  hipMemsetAsync(deg,   0, (size_t)NN*sizeof(int), stream);
  hipMemsetAsync(fillc, 0, (size_t)NN*sizeof(int), stream);

  int gE = (NE + 255)/256;
  int nchunks = (NN + 1023)/1024;
  k_detect<<<1, 64, 0, stream>>>((const long long*)ei, flag);
  k_convert<<<gE, 256, 0, stream>>>(ei, flag, src32, dst32);
  k_count<<<gE, 256, 0, stream>>>(dst32, deg);
  k_scan1<<<nchunks, 1024, 0, stream>>>(deg, rowptr, sums);
  k_scan2<<<1, 64, 0, stream>>>(sums, nchunks);
  k_scan3<<<(NN + 255)/256, 256, 0, stream>>>(rowptr, sums);
  k_fill<<<gE, 256, 0, stream>>>(src32, dst32, rowptr, fillc, colsrc, epos);
  k_gemm1<<<NN/8, 256, 0, stream>>>(x, W1, as1w, ad1w, h1b, as1, ad1);
  k_es<<<gE, 256, 0, stream>>>(src32, dst32, epos, as1, ad1, es4);
  k_agg1<<<NN, 128, 0, stream>>>(h1b, es4, as1, ad1, rowptr, colsrc, b1, h1a);
  k_gemm2<<<(NN + 255)/256, 256, 0, stream>>>(h1a, W2, as2w, ad2w, h2, a2s, a2d);
  k_agg2<<<NN, 64, 0, stream>>>(h2, a2s, a2d, rowptr, colsrc, b2, out);
}